// Round 6
// baseline (221.019 us; speedup 1.0000x reference)
//
#include <hip/hip_runtime.h>
#include <hip/hip_bf16.h>
#include <hip/hip_cooperative_groups.h>
#include <math.h>

namespace cg = cooperative_groups;

// loss = w * mean((sim_o - sim_t)^2);  ||OO^T - TT^T||_F^2 =
//   ||O^T O||^2 + ||T^T T||^2 - 2||O^T T||^2   (diag mask is a no-op).
// Single cooperative kernel (round-5 evidence: 4 small kernels were dominated
// by ~3-4us/node graph dispatch gaps):
//   A: normalize + bf16 + transpose -> obt [f][k]      (512 blocks)
//   B: MFMA gram partials per K-chunk (round-5 logic)  (512 blocks)
//   C: partial-sum over chunks + Frobenius -> ws[0]    (blocks 0..191)
//   D: out = ws[0] * w / N^2                           (block 0)

#define N_ROWS 8192
#define DDIM   256
#define NC     32                  // K chunks
#define KC     (N_ROWS / NC)       // 256 rows / chunk
#define KS     64                  // k rows staged per iter
#define NITER  (KC / KS)           // 4
#define PART_STRIDE 196608         // 3 grams * 16 tiles * 4096 ushorts / chunk

// ushort-space offsets into ws (ws[0] float = scalar acc)
#define OBT_UOFF  32
#define MAT_USZ   (DDIM * N_ROWS)            // 2,097,152 ushorts per matrix
#define PART_UOFF (OBT_UOFF + 2 * MAT_USZ)

typedef __bf16 bf16x8 __attribute__((ext_vector_type(8)));
typedef short  short8 __attribute__((ext_vector_type(8)));
typedef unsigned short ushort8 __attribute__((ext_vector_type(8)));
typedef float  f32x16 __attribute__((ext_vector_type(16)));
typedef unsigned int u32;

__device__ inline unsigned short f2bu(float x) {
    __hip_bfloat16 h = __float2bfloat16(x);
    return __builtin_bit_cast(unsigned short, h);
}
__device__ inline float u2f(unsigned short u) {
    unsigned int v = ((unsigned int)u) << 16;
    return __builtin_bit_cast(float, v);
}
__device__ inline void gload_lds16(const void* g, void* l) {
    __builtin_amdgcn_global_load_lds(
        (const __attribute__((address_space(1))) u32*)g,
        (__attribute__((address_space(3))) u32*)l, 16, 0, 0);
}

__global__ __launch_bounds__(256) void fused_kernel(const float* __restrict__ O,
                                                    const float* __restrict__ T,
                                                    const float* __restrict__ W,
                                                    float* __restrict__ out,
                                                    float* __restrict__ ws) {
    cg::grid_group grid = cg::this_grid();

    __shared__ union {
        unsigned short lt[32][260];                   // phase A transpose tile
        unsigned short slabs[2][4][KS * 64];          // phase B: 64 KiB dbuf
    } sh;

    int tid = threadIdx.x;
    int bid = blockIdx.x;

    // ---------------- Phase A: normalize + bf16 + transpose ----------------
    {
        if (bid == 0 && tid == 0) ws[0] = 0.0f;
        const float* src = (bid & 1) ? T : O;
        unsigned short* dst =
            (unsigned short*)ws + OBT_UOFF + (size_t)(bid & 1) * MAT_USZ;
        int kb = (bid >> 1) * 32;
        int w = tid >> 6, l = tid & 63;
        #pragma unroll
        for (int j = 0; j < 8; ++j) {
            int r = j * 4 + w;
            float4 v = *reinterpret_cast<const float4*>(
                src + (size_t)(kb + r) * DDIM + l * 4);
            float ss = v.x * v.x + v.y * v.y + v.z * v.z + v.w * v.w;
            #pragma unroll
            for (int off = 32; off > 0; off >>= 1) ss += __shfl_xor(ss, off);
            float inv = 1.0f / fmaxf(sqrtf(ss), 1e-8f);
            ushort4 u;
            u.x = f2bu(v.x * inv); u.y = f2bu(v.y * inv);
            u.z = f2bu(v.z * inv); u.w = f2bu(v.w * inv);
            *reinterpret_cast<ushort4*>(&sh.lt[r][l * 4]) = u;
        }
        __syncthreads();
        int f = tid;
        #pragma unroll
        for (int s = 0; s < 4; ++s) {                 // 4 x 16B stores (1 line)
            ushort8 u;
            #pragma unroll
            for (int j = 0; j < 8; ++j) u[j] = sh.lt[s * 8 + j][f];
            *reinterpret_cast<ushort8*>(&dst[(size_t)f * N_ROWS + kb + s * 8]) = u;
        }
    }

    grid.sync();

    // ---------------- Phase B: MFMA gram partials ----------------
    {
        const unsigned short* obt = (const unsigned short*)ws + OBT_UOFF;
        unsigned short* part = (unsigned short*)ws + PART_UOFF;

        int ti = bid & 15, c = bid >> 4;              // tile, K-chunk
        int tm = ti >> 2, tn = ti & 3;
        int lane = tid & 63, wid = tid >> 6;
        int wm = wid >> 1, wn = wid & 1;
        int k0 = c * KC;

        f32x16 acc_oo, acc_tt, acc_ot;
        #pragma unroll
        for (int e = 0; e < 16; ++e) {
            acc_oo[e] = 0.f; acc_tt[e] = 0.f; acc_ot[e] = 0.f;
        }

        // wave wid stages slab wid: {0:O_m, 1:O_n, 2:T_m, 3:T_n}
        int sl = wid;
        int mat = sl >> 1;
        int ft = (sl & 1) ? tn : tm;
        const unsigned short* slab_src =
            obt + (size_t)mat * MAT_USZ + (size_t)(ft * 64) * N_ROWS;
        int frow = lane >> 3;
        int swz8 = ((lane & 7) ^ (frow & 7)) * 8;     // XOR: inverse == forward

        auto stage = [&](int buf, int it) {
            int kb = k0 + it * KS;
            const unsigned short* base =
                slab_src + kb + (size_t)frow * N_ROWS + swz8;
            unsigned short* ld = &sh.slabs[buf][sl][0];
            #pragma unroll
            for (int i = 0; i < 8; ++i)
                gload_lds16(base + (size_t)(i * 8) * N_ROWS, ld + i * 512);
        };

        int fm = wm * 32 + (lane & 31);
        int fn = wn * 32 + (lane & 31);
        int jhalf = lane >> 5;
        auto frag = [&](int buf, int s, int fl, int kk) -> bf16x8 {
            int j0 = kk * 2 + jhalf;
            const unsigned short* p =
                &sh.slabs[buf][s][fl * 64 + ((j0 ^ (fl & 7)) * 8)];
            return __builtin_bit_cast(bf16x8,
                       *reinterpret_cast<const short8*>(p));
        };

        stage(0, 0);
        __syncthreads();
        int cur = 0;
        for (int it = 0; it < NITER; ++it) {
            if (it + 1 < NITER) stage(cur ^ 1, it + 1);
            #pragma unroll
            for (int kk = 0; kk < 4; ++kk) {
                bf16x8 ao = frag(cur, 0, fm, kk);
                bf16x8 bo = frag(cur, 1, fn, kk);
                bf16x8 at = frag(cur, 2, fm, kk);
                bf16x8 bt = frag(cur, 3, fn, kk);
                acc_oo = __builtin_amdgcn_mfma_f32_32x32x16_bf16(ao, bo, acc_oo, 0, 0, 0);
                acc_tt = __builtin_amdgcn_mfma_f32_32x32x16_bf16(at, bt, acc_tt, 0, 0, 0);
                acc_ot = __builtin_amdgcn_mfma_f32_32x32x16_bf16(ao, bt, acc_ot, 0, 0, 0);
            }
            __syncthreads();   // drains vmcnt+lgkm for both buffers
            cur ^= 1;
        }

        // C/D layout (m74/m101): col=lane&31, row=(reg&3)+8*(reg>>2)+4*(lane>>5)
        unsigned int tb = (unsigned int)(c * 16 + ti) * 3;
        #pragma unroll
        for (int reg = 0; reg < 16; ++reg) {
            int row = (reg & 3) + 8 * (reg >> 2) + ((lane >> 5) << 2);
            int col = lane & 31;
            int idx = (wm * 32 + row) * 64 + (wn * 32 + col);
            part[(size_t)(tb + 0) * 4096 + idx] = f2bu(acc_oo[reg]);
            part[(size_t)(tb + 1) * 4096 + idx] = f2bu(acc_tt[reg]);
            part[(size_t)(tb + 2) * 4096 + idx] = f2bu(acc_ot[reg]);
        }
    }

    grid.sync();

    // ---------------- Phase C: chunk-sum + Frobenius combine ----------------
    {
        const unsigned short* part = (const unsigned short*)ws + PART_UOFF;
        int gid = bid * 256 + tid;
        if (gid < 49152) {                 // blocks 0..191 participate
            int base = gid * 4;
            float s0 = 0.f, s1 = 0.f, s2 = 0.f, s3 = 0.f;
            for (int cc = 0; cc < NC; ++cc) {
                ushort4 u = *reinterpret_cast<const ushort4*>(
                    &part[(size_t)cc * PART_STRIDE + base]);
                s0 += u2f(u.x); s1 += u2f(u.y); s2 += u2f(u.z); s3 += u2f(u.w);
            }
            int g = (base >> 12) % 3;      // layout: (ti*3+g)*4096 + e
            float s = s0 * s0 + s1 * s1 + s2 * s2 + s3 * s3;
            if (g == 2) s = -2.0f * s;
            #pragma unroll
            for (int off = 32; off > 0; off >>= 1) s += __shfl_down(s, off);
            __shared__ float wsum[4];
            int lane = tid & 63, w = tid >> 6;
            if (lane == 0) wsum[w] = s;
            __syncthreads();
            if (tid == 0)
                atomicAdd(&ws[0], wsum[0] + wsum[1] + wsum[2] + wsum[3]);
        }
    }

    grid.sync();

    // ---------------- Phase D: scale + fp32 scalar out ----------------
    if (bid == 0 && tid == 0)
        out[0] = ws[0] * W[0] / ((float)N_ROWS * (float)N_ROWS);
}

extern "C" void kernel_launch(void* const* d_in, const int* in_sizes, int n_in,
                              void* d_out, int out_size, void* d_ws, size_t ws_size,
                              hipStream_t stream) {
    const float* O = (const float*)d_in[0];
    const float* T = (const float*)d_in[1];
    const float* W = (const float*)d_in[2];
    float* out = (float*)d_out;
    float* ws = (float*)d_ws;

    void* args[] = { (void*)&O, (void*)&T, (void*)&W, (void*)&out, (void*)&ws };
    hipLaunchCooperativeKernel((const void*)fused_kernel, dim3(512), dim3(256),
                               args, 0, stream);
}

// Round 7
// 94.104 us; speedup vs baseline: 2.3487x; 2.3487x over previous
//
#include <hip/hip_runtime.h>
#include <hip/hip_bf16.h>
#include <math.h>

// loss = w * mean((sim_o - sim_t)^2);  ||OO^T - TT^T||_F^2 =
//   ||O^T O||^2 + ||T^T T||^2 - 2||O^T T||^2   (diag mask is a no-op).
// Two launches (round-6: cooperative grid.sync costs ~65us each — never again):
//   K1: normalize + bf16 + transpose -> obt [f][k] (coalesced writes via
//       XOR-swizzled LDS tile)
//   K2: MFMA gram partials -> hand-rolled release/acquire barrier ->
//       distributed reduce -> last-block finalize. 32KB LDS = 4 blocks/CU.

#define N_ROWS 8192
#define DDIM   256
#define NC     32                  // K chunks
#define KC     (N_ROWS / NC)       // 256 rows / chunk
#define KS     32                  // k rows staged per iter
#define NITER  (KC / KS)           // 8
#define PART_STRIDE 196608         // ushorts per chunk = 3 grams * 16 tiles * 4096
#define NGRAM  512
#define NRED   192

// ws layout: float ws[0] = scalar acc; uint ctr[2] at ws[4..5];
// obt (bf16, 2 matrices [f][k]) at OBT_UOFF ushorts; partials after.
#define OBT_UOFF  32
#define MAT_USZ   (DDIM * N_ROWS)            // 2,097,152 ushorts per matrix
#define PART_UOFF (OBT_UOFF + 2 * MAT_USZ)

typedef __bf16 bf16x8 __attribute__((ext_vector_type(8)));
typedef short  short8 __attribute__((ext_vector_type(8)));
typedef unsigned short ushort8 __attribute__((ext_vector_type(8)));
typedef float  f32x16 __attribute__((ext_vector_type(16)));
typedef unsigned int u32;

__device__ inline unsigned short f2bu(float x) {
    __hip_bfloat16 h = __float2bfloat16(x);
    return __builtin_bit_cast(unsigned short, h);
}
__device__ inline float u2f(unsigned short u) {
    unsigned int v = ((unsigned int)u) << 16;
    return __builtin_bit_cast(float, v);
}
__device__ inline void gload_lds16(const void* g, void* l) {
    __builtin_amdgcn_global_load_lds(
        (const __attribute__((address_space(1))) u32*)g,
        (__attribute__((address_space(3))) u32*)l, 16, 0, 0);
}

// ---- K1: normalize + bf16 + transpose ----
// 256 blocks: (b&1) matrix, (b>>1)*64 k-rows. LDS tile XOR-swizzled at
// f-octet granularity (octet ^= k&31): load-writes <=4-way, read-side
// ~2-way, and global writes are 8x128B full lines per wave instr.
__global__ __launch_bounds__(256) void transpose_kernel(const float* __restrict__ O,
                                                        const float* __restrict__ T,
                                                        float* __restrict__ ws) {
    int tid = threadIdx.x;
    if (blockIdx.x == 0 && tid == 0) {
        ws[0] = 0.0f;
        ((u32*)(ws + 4))[0] = 0u;
        ((u32*)(ws + 4))[1] = 0u;
    }
    int b = blockIdx.x;
    const float* src = (b & 1) ? T : O;
    unsigned short* dst =
        (unsigned short*)ws + OBT_UOFF + (size_t)(b & 1) * MAT_USZ;
    int kb = (b >> 1) * 64;

    __shared__ unsigned short lt[64 * 256];   // 32 KiB, swizzled
    int w = tid >> 6, l = tid & 63;
    #pragma unroll
    for (int j = 0; j < 16; ++j) {
        int r = j * 4 + w;
        float4 v = *reinterpret_cast<const float4*>(
            src + (size_t)(kb + r) * DDIM + l * 4);
        float ss = v.x * v.x + v.y * v.y + v.z * v.z + v.w * v.w;
        #pragma unroll
        for (int off = 32; off > 0; off >>= 1) ss += __shfl_xor(ss, off);
        float inv = 1.0f / fmaxf(sqrtf(ss), 1e-8f);
        ushort4 u;
        u.x = f2bu(v.x * inv); u.y = f2bu(v.y * inv);
        u.z = f2bu(v.z * inv); u.w = f2bu(v.w * inv);
        // f0 = 4l -> octet l>>1, elem (l&1)*4; octet XOR (r&31)
        int idx = r * 256 + ((((l >> 1) ^ (r & 31)) << 3) | ((l & 1) << 2));
        *reinterpret_cast<ushort4*>(&lt[idx]) = u;
    }
    __syncthreads();
    #pragma unroll
    for (int s = 0; s < 8; ++s) {
        int f = (tid >> 3) + 32 * s;
        int kc = tid & 7;
        ushort8 u;
        #pragma unroll
        for (int j = 0; j < 8; ++j) {
            int k = kc * 8 + j;
            u[j] = lt[k * 256 + ((((f >> 3) ^ (k & 31)) << 3) | (f & 7))];
        }
        *reinterpret_cast<ushort8*>(&dst[(size_t)f * N_ROWS + kb + kc * 8]) = u;
    }
}

// ---- K2: MFMA gram partials + in-kernel barrier + reduce + finalize ----
// 512 blocks = 16 tiles (4x4 of 64x64) x 32 chunks; 4 waves (2x2 of 32x32).
// Slabs [f 64][k 32] bf16, k-octets XOR-swizzled by (f&3) via pre-swizzled
// global src (LDS dest linear, as global_load_lds requires).
__global__ __launch_bounds__(256) void gram_kernel(const float* __restrict__ W,
                                                   float* __restrict__ out,
                                                   float* __restrict__ ws) {
    const unsigned short* obt = (const unsigned short*)ws + OBT_UOFF;
    unsigned short* part = (unsigned short*)ws + PART_UOFF;
    u32* ctr = (u32*)(ws + 4);

    int bid = blockIdx.x;
    int ti = bid & 15, c = bid >> 4;
    int tm = ti >> 2, tn = ti & 3;
    int tid = threadIdx.x, lane = tid & 63, wid = tid >> 6;
    int wm = wid >> 1, wn = wid & 1;
    int k0 = c * KC;

    __shared__ __align__(16) unsigned short slabs[2][4][64 * KS];   // 32 KiB
    __shared__ float wsum[4];

    f32x16 acc_oo, acc_tt, acc_ot;
    #pragma unroll
    for (int e = 0; e < 16; ++e) { acc_oo[e] = 0.f; acc_tt[e] = 0.f; acc_ot[e] = 0.f; }

    // wave wid stages slab wid: {0:O_m, 1:O_n, 2:T_m, 3:T_n}
    int sl = wid;
    int mat = sl >> 1;
    int ft = (sl & 1) ? tn : tm;
    int frow = lane >> 2;                 // f-row 0..15 per stage instr
    int koct = lane & 3;                  // k-octet slot
    const unsigned short* slab_src =
        obt + (size_t)mat * MAT_USZ + (size_t)(ft * 64 + frow) * N_ROWS
        + ((koct ^ (frow & 3)) * 8);      // XOR: inverse == forward

    auto stage = [&](int buf, int it) {
        int kb = k0 + it * KS;
        unsigned short* ld = &slabs[buf][sl][0];
        #pragma unroll
        for (int i = 0; i < 4; ++i)       // f-rows i*16+frow
            gload_lds16(slab_src + kb + (size_t)(i * 16) * N_ROWS, ld + i * 512);
    };

    int fm = wm * 32 + (lane & 31);
    int fn = wn * 32 + (lane & 31);
    int jhalf = lane >> 5;
    auto frag = [&](int buf, int s, int fl, int kk) -> bf16x8 {
        int j0 = kk * 2 + jhalf;          // k-octet 0..3
        const unsigned short* p = &slabs[buf][s][fl * KS + ((j0 ^ (fl & 3)) * 8)];
        return __builtin_bit_cast(bf16x8, *reinterpret_cast<const short8*>(p));
    };

    stage(0, 0);
    __syncthreads();
    int cur = 0;
    for (int it = 0; it < NITER; ++it) {
        if (it + 1 < NITER) stage(cur ^ 1, it + 1);
        #pragma unroll
        for (int kk = 0; kk < 2; ++kk) {
            bf16x8 ao = frag(cur, 0, fm, kk);
            bf16x8 bo = frag(cur, 1, fn, kk);
            bf16x8 at = frag(cur, 2, fm, kk);
            bf16x8 bt = frag(cur, 3, fn, kk);
            acc_oo = __builtin_amdgcn_mfma_f32_32x32x16_bf16(ao, bo, acc_oo, 0, 0, 0);
            acc_tt = __builtin_amdgcn_mfma_f32_32x32x16_bf16(at, bt, acc_tt, 0, 0, 0);
            acc_ot = __builtin_amdgcn_mfma_f32_32x32x16_bf16(ao, bt, acc_ot, 0, 0, 0);
        }
        __syncthreads();
        cur ^= 1;
    }

    // partial write; C/D layout (m74/m101): col=lane&31, row=(reg&3)+8*(reg>>2)+4*(lane>>5)
    unsigned int tb = (unsigned int)(c * 16 + ti) * 3;
    #pragma unroll
    for (int reg = 0; reg < 16; ++reg) {
        int row = (reg & 3) + 8 * (reg >> 2) + ((lane >> 5) << 2);
        int col = lane & 31;
        int idx = (wm * 32 + row) * 64 + (wn * 32 + col);
        part[(size_t)(tb + 0) * 4096 + idx] = f2bu(acc_oo[reg]);
        part[(size_t)(tb + 1) * 4096 + idx] = f2bu(acc_tt[reg]);
        part[(size_t)(tb + 2) * 4096 + idx] = f2bu(acc_ot[reg]);
    }

    // ---- release: publish partials, count this block done ----
    __syncthreads();
    if (tid == 0) {
        __threadfence();                          // agent-scope release
        atomicAdd(&ctr[0], 1u);
    }
    if (bid >= NRED) return;                      // non-reducers exit (frees slots)

    // ---- acquire: spin until all 512 gram blocks published ----
    if (tid == 0) {
        while (__hip_atomic_load(&ctr[0], __ATOMIC_ACQUIRE,
                                 __HIP_MEMORY_SCOPE_AGENT) < NGRAM)
            __builtin_amdgcn_s_sleep(2);
    }
    __syncthreads();
    __threadfence();                              // acquire side

    // ---- distributed reduce: sum partials over chunks, square, combine ----
    {
        int gid = bid * 256 + tid;                // 49152 threads
        int base = gid * 4;
        float s0 = 0.f, s1 = 0.f, s2 = 0.f, s3 = 0.f;
        for (int cc = 0; cc < NC; ++cc) {
            ushort4 u = *reinterpret_cast<const ushort4*>(
                &part[(size_t)cc * PART_STRIDE + base]);
            s0 += u2f(u.x); s1 += u2f(u.y); s2 += u2f(u.z); s3 += u2f(u.w);
        }
        int g = (base >> 12) % 3;                 // layout: ((c16ti)*3+g)*4096+e
        float s = s0 * s0 + s1 * s1 + s2 * s2 + s3 * s3;
        if (g == 2) s = -2.0f * s;
        #pragma unroll
        for (int off = 32; off > 0; off >>= 1) s += __shfl_down(s, off);
        int l = tid & 63, w = tid >> 6;
        if (l == 0) wsum[w] = s;
        __syncthreads();
        if (tid == 0) {
            atomicAdd(&ws[0], wsum[0] + wsum[1] + wsum[2] + wsum[3]);
            __threadfence();
            unsigned int r = atomicAdd(&ctr[1], 1u);
            if (r == NRED - 1) {                  // last reducer finalizes
                float v = __hip_atomic_load(&ws[0], __ATOMIC_ACQUIRE,
                                            __HIP_MEMORY_SCOPE_AGENT);
                out[0] = v * W[0] / ((float)N_ROWS * (float)N_ROWS);
            }
        }
    }
}

extern "C" void kernel_launch(void* const* d_in, const int* in_sizes, int n_in,
                              void* d_out, int out_size, void* d_ws, size_t ws_size,
                              hipStream_t stream) {
    const float* O = (const float*)d_in[0];
    const float* T = (const float*)d_in[1];
    const float* W = (const float*)d_in[2];
    float* out = (float*)d_out;
    float* ws = (float*)d_ws;

    transpose_kernel<<<256, 256, 0, stream>>>(O, T, ws);
    gram_kernel<<<NGRAM, 256, 0, stream>>>(W, out, ws);
}

// Round 8
// 33.119 us; speedup vs baseline: 6.6735x; 2.8414x over previous
//
#include <hip/hip_runtime.h>
#include <hip/hip_bf16.h>
#include <math.h>

// loss = w * mean((sim_o - sim_t)^2);  ||OO^T - TT^T||_F^2 =
//   ||O^T O||^2 + ||T^T T||^2 - 2||O^T T||^2   (diag mask is a no-op).
// THREE launches, ZERO global barriers (rounds 6+7: any grid-wide barrier —
// grid.sync or hand-rolled spin — costs ~70us on 8-XCD MI355X):
//   K1 transpose: normalize + bf16 + transpose -> obt [f][k]
//   K2 gram: MFMA partials per K-chunk (round-5 verified core + XCD swizzle)
//   K3 reduce: chunk-sum + Frobenius combine; LAST block finalizes out[0].

#define N_ROWS 8192
#define DDIM   256
#define NC     32                  // K chunks
#define KC     (N_ROWS / NC)       // 256 rows / chunk
#define KS     64                  // k rows staged per iter
#define NITER  (KC / KS)           // 4
#define PART_STRIDE 196608         // ushorts per chunk = 3 grams * 16 tiles * 4096
#define NRED   192

// ws layout: float ws[0] = scalar acc; u32 ctr at ws[4];
// obt (bf16, 2 matrices [f][k]) at OBT_UOFF ushorts; partials after.
#define OBT_UOFF  32
#define MAT_USZ   (DDIM * N_ROWS)            // 2,097,152 ushorts per matrix
#define PART_UOFF (OBT_UOFF + 2 * MAT_USZ)

typedef __bf16 bf16x8 __attribute__((ext_vector_type(8)));
typedef short  short8 __attribute__((ext_vector_type(8)));
typedef unsigned short ushort8 __attribute__((ext_vector_type(8)));
typedef float  f32x16 __attribute__((ext_vector_type(16)));
typedef unsigned int u32;

__device__ inline unsigned short f2bu(float x) {
    __hip_bfloat16 h = __float2bfloat16(x);
    return __builtin_bit_cast(unsigned short, h);
}
__device__ inline float u2f(unsigned short u) {
    unsigned int v = ((unsigned int)u) << 16;
    return __builtin_bit_cast(float, v);
}
__device__ inline void gload_lds16(const void* g, void* l) {
    __builtin_amdgcn_global_load_lds(
        (const __attribute__((address_space(1))) u32*)g,
        (__attribute__((address_space(3))) u32*)l, 16, 0, 0);
}

// ---- K1: normalize + bf16 + transpose ----
// 256 blocks: (b&1) matrix, (b>>1)*64 k-rows. LDS tile XOR-swizzled at
// f-octet granularity (octet ^= k&31): global writes are full 128B lines.
__global__ __launch_bounds__(256) void transpose_kernel(const float* __restrict__ O,
                                                        const float* __restrict__ T,
                                                        float* __restrict__ ws) {
    int tid = threadIdx.x;
    if (blockIdx.x == 0 && tid == 0) {
        ws[0] = 0.0f;
        ((u32*)(ws + 4))[0] = 0u;
    }
    int b = blockIdx.x;
    const float* src = (b & 1) ? T : O;
    unsigned short* dst =
        (unsigned short*)ws + OBT_UOFF + (size_t)(b & 1) * MAT_USZ;
    int kb = (b >> 1) * 64;

    __shared__ unsigned short lt[64 * 256];   // 32 KiB, swizzled
    int w = tid >> 6, l = tid & 63;
    #pragma unroll
    for (int j = 0; j < 16; ++j) {
        int r = j * 4 + w;
        float4 v = *reinterpret_cast<const float4*>(
            src + (size_t)(kb + r) * DDIM + l * 4);
        float ss = v.x * v.x + v.y * v.y + v.z * v.z + v.w * v.w;
        #pragma unroll
        for (int off = 32; off > 0; off >>= 1) ss += __shfl_xor(ss, off);
        float inv = 1.0f / fmaxf(sqrtf(ss), 1e-8f);
        ushort4 u;
        u.x = f2bu(v.x * inv); u.y = f2bu(v.y * inv);
        u.z = f2bu(v.z * inv); u.w = f2bu(v.w * inv);
        // f0 = 4l -> octet l>>1, elem (l&1)*4; octet XOR (r&31)
        int idx = r * 256 + ((((l >> 1) ^ (r & 31)) << 3) | ((l & 1) << 2));
        *reinterpret_cast<ushort4*>(&lt[idx]) = u;
    }
    __syncthreads();
    #pragma unroll
    for (int s = 0; s < 8; ++s) {
        int f = (tid >> 3) + 32 * s;
        int kc = tid & 7;
        ushort8 u;
        #pragma unroll
        for (int j = 0; j < 8; ++j) {
            int k = kc * 8 + j;
            u[j] = lt[k * 256 + ((((f >> 3) ^ (k & 31)) << 3) | (f & 7))];
        }
        *reinterpret_cast<ushort8*>(&dst[(size_t)f * N_ROWS + kb + kc * 8]) = u;
    }
}

// ---- K2: MFMA gram partials (round-5 core, no barrier) ----
// 512 blocks; XCD-grouped decode: chunk = (bid&7)*4 + (bid>>7), ti = (bid>>3)&15
// -> all 16 tile-blocks of a chunk share bid%8, i.e. one XCD: slab re-reads
// hit that XCD's L2. 4 waves (2x2 of 32x32); slabs [f 64][k 64] bf16,
// k-octets XOR-swizzled by (f&7) via pre-swizzled global src (linear LDS dest).
__global__ __launch_bounds__(256) void gram_kernel(float* __restrict__ ws) {
    const unsigned short* obt = (const unsigned short*)ws + OBT_UOFF;
    unsigned short* part = (unsigned short*)ws + PART_UOFF;

    int bid = blockIdx.x;
    int c  = (bid & 7) * 4 + (bid >> 7);          // K-chunk 0..31
    int ti = (bid >> 3) & 15;                     // tile 0..15
    int tm = ti >> 2, tn = ti & 3;
    int tid = threadIdx.x, lane = tid & 63, wid = tid >> 6;
    int wm = wid >> 1, wn = wid & 1;
    int k0 = c * KC;

    __shared__ __align__(16) unsigned short slabs[2][4][64 * KS];   // 64 KiB

    f32x16 acc_oo, acc_tt, acc_ot;
    #pragma unroll
    for (int e = 0; e < 16; ++e) { acc_oo[e] = 0.f; acc_tt[e] = 0.f; acc_ot[e] = 0.f; }

    // wave wid stages slab wid: {0:O_m, 1:O_n, 2:T_m, 3:T_n}
    int sl = wid;
    int mat = sl >> 1;
    int ft = (sl & 1) ? tn : tm;
    int frow = lane >> 3;                         // f-row 0..7 per stage instr
    int swz8 = ((lane & 7) ^ (frow & 7)) * 8;     // XOR: inverse == forward
    const unsigned short* slab_src =
        obt + (size_t)mat * MAT_USZ + (size_t)(ft * 64 + frow) * N_ROWS + swz8;

    auto stage = [&](int buf, int it) {
        int kb = k0 + it * KS;
        unsigned short* ld = &slabs[buf][sl][0];
        #pragma unroll
        for (int i = 0; i < 8; ++i)               // f-rows i*8+frow, 1KB/instr
            gload_lds16(slab_src + kb + (size_t)(i * 8) * N_ROWS, ld + i * 512);
    };

    int fm = wm * 32 + (lane & 31);
    int fn = wn * 32 + (lane & 31);
    int jhalf = lane >> 5;
    auto frag = [&](int buf, int s, int fl, int kk) -> bf16x8 {
        int j0 = kk * 2 + jhalf;                  // k-octet 0..7
        const unsigned short* p = &slabs[buf][s][fl * KS + ((j0 ^ (fl & 7)) * 8)];
        return __builtin_bit_cast(bf16x8, *reinterpret_cast<const short8*>(p));
    };

    stage(0, 0);
    __syncthreads();
    int cur = 0;
    for (int it = 0; it < NITER; ++it) {
        if (it + 1 < NITER) stage(cur ^ 1, it + 1);
        #pragma unroll
        for (int kk = 0; kk < 4; ++kk) {
            bf16x8 ao = frag(cur, 0, fm, kk);
            bf16x8 bo = frag(cur, 1, fn, kk);
            bf16x8 at = frag(cur, 2, fm, kk);
            bf16x8 bt = frag(cur, 3, fn, kk);
            acc_oo = __builtin_amdgcn_mfma_f32_32x32x16_bf16(ao, bo, acc_oo, 0, 0, 0);
            acc_tt = __builtin_amdgcn_mfma_f32_32x32x16_bf16(at, bt, acc_tt, 0, 0, 0);
            acc_ot = __builtin_amdgcn_mfma_f32_32x32x16_bf16(ao, bt, acc_ot, 0, 0, 0);
        }
        __syncthreads();                          // drains vmcnt+lgkm
        cur ^= 1;
    }

    // C/D layout (m74/m101): col=lane&31, row=(reg&3)+8*(reg>>2)+4*(lane>>5)
    unsigned int tb = (unsigned int)(c * 16 + ti) * 3;
    #pragma unroll
    for (int reg = 0; reg < 16; ++reg) {
        int row = (reg & 3) + 8 * (reg >> 2) + ((lane >> 5) << 2);
        int col = lane & 31;
        int idx = (wm * 32 + row) * 64 + (wn * 32 + col);
        part[(size_t)(tb + 0) * 4096 + idx] = f2bu(acc_oo[reg]);
        part[(size_t)(tb + 1) * 4096 + idx] = f2bu(acc_tt[reg]);
        part[(size_t)(tb + 2) * 4096 + idx] = f2bu(acc_ot[reg]);
    }
}

// ---- K3: chunk-sum + Frobenius combine; last block finalizes ----
__global__ __launch_bounds__(256) void reduce_kernel(const float* __restrict__ W,
                                                     float* __restrict__ out,
                                                     float* __restrict__ ws) {
    const unsigned short* part = (const unsigned short*)ws + PART_UOFF;
    u32* ctr = (u32*)(ws + 4);
    int tid = threadIdx.x;
    int gid = blockIdx.x * 256 + tid;             // 49152 threads
    int base = gid * 4;
    float s0 = 0.f, s1 = 0.f, s2 = 0.f, s3 = 0.f;
    for (int cc = 0; cc < NC; ++cc) {
        ushort4 u = *reinterpret_cast<const ushort4*>(
            &part[(size_t)cc * PART_STRIDE + base]);
        s0 += u2f(u.x); s1 += u2f(u.y); s2 += u2f(u.z); s3 += u2f(u.w);
    }
    int g = (base >> 12) % 3;                     // layout: ((c*16+ti)*3+g)*4096+e
    float s = s0 * s0 + s1 * s1 + s2 * s2 + s3 * s3;
    if (g == 2) s = -2.0f * s;
    #pragma unroll
    for (int off = 32; off > 0; off >>= 1) s += __shfl_down(s, off);
    __shared__ float wsum[4];
    int l = tid & 63, w = tid >> 6;
    if (l == 0) wsum[w] = s;
    __syncthreads();
    if (tid == 0) {
        atomicAdd(&ws[0], wsum[0] + wsum[1] + wsum[2] + wsum[3]);
        __threadfence();
        unsigned int r = atomicAdd(&ctr[0], 1u);
        if (r == NRED - 1) {                      // last finishing block
            float v = __hip_atomic_load(&ws[0], __ATOMIC_ACQUIRE,
                                        __HIP_MEMORY_SCOPE_AGENT);
            out[0] = v * W[0] / ((float)N_ROWS * (float)N_ROWS);
        }
    }
}

extern "C" void kernel_launch(void* const* d_in, const int* in_sizes, int n_in,
                              void* d_out, int out_size, void* d_ws, size_t ws_size,
                              hipStream_t stream) {
    const float* O = (const float*)d_in[0];
    const float* T = (const float*)d_in[1];
    const float* W = (const float*)d_in[2];
    float* out = (float*)d_out;
    float* ws = (float*)d_ws;

    transpose_kernel<<<256, 256, 0, stream>>>(O, T, ws);
    gram_kernel<<<512, 256, 0, stream>>>(ws);
    reduce_kernel<<<NRED, 256, 0, stream>>>(W, out, ws);
}